// Round 1
// baseline (152.095 us; speedup 1.0000x reference)
//
#include <hip/hip_runtime.h>
#include <math.h>

#define LOG2PI_F 1.8378770664093453f
#define EXP_NEG1 0.36787944117144233f

// ws layout (floats): [0]=recon_sum [1]=lqzx_sum [2]=lprior_sum [3]=lqz_sum [4]=lqzp_sum

__global__ __launch_bounds__(64) void k_zero(float* acc) {
    if (threadIdx.x < 16) acc[threadIdx.x] = 0.0f;
}

__global__ __launch_bounds__(256) void k_recon(const float4* __restrict__ x,
                                               const float4* __restrict__ r,
                                               float* __restrict__ acc, int n4) {
    int idx = blockIdx.x * 256 + threadIdx.x;
    float s = 0.0f;
    if (idx < n4) {
        float4 a = x[idx], b = r[idx];
        s = fabsf(a.x - b.x) + fabsf(a.y - b.y) + fabsf(a.z - b.z) + fabsf(a.w - b.w);
    }
    #pragma unroll
    for (int off = 32; off > 0; off >>= 1) s += __shfl_down(s, off);
    __shared__ float red[4];
    int lane = threadIdx.x & 63, wave = threadIdx.x >> 6;
    if (lane == 0) red[wave] = s;
    __syncthreads();
    if (threadIdx.x == 0) {
        atomicAdd(&acc[0], red[0] + red[1] + red[2] + red[3]);
    }
}

// per-element log q(z|x) and log p(z) sums  (sum over all (i,d) == sum over i of row sums)
__global__ __launch_bounds__(256) void k_row(const float* __restrict__ mu,
                                             const float* __restrict__ lv,
                                             const float* __restrict__ z,
                                             float* __restrict__ acc, int n) {
    int idx = blockIdx.x * 256 + threadIdx.x;
    float a = 0.0f, b = 0.0f;
    if (idx < n) {
        float m = mu[idx], l = lv[idx], zz = z[idx];
        float t = zz - m;
        a = -0.5f * (fmaf(t * t, __expf(-l), l) + LOG2PI_F);
        b = -0.5f * (fmaf(zz * zz, EXP_NEG1, 1.0f) + LOG2PI_F);
    }
    #pragma unroll
    for (int off = 32; off > 0; off >>= 1) {
        a += __shfl_down(a, off);
        b += __shfl_down(b, off);
    }
    __shared__ float reda[4], redb[4];
    int lane = threadIdx.x & 63, wave = threadIdx.x >> 6;
    if (lane == 0) { reda[wave] = a; redb[wave] = b; }
    __syncthreads();
    if (threadIdx.x == 0) {
        atomicAdd(&acc[1], reda[0] + reda[1] + reda[2] + reda[3]);
        atomicAdd(&acc[2], redb[0] + redb[1] + redb[2] + redb[3]);
    }
}

// One block per row i. Threads split the j loop. Linear-domain logsumexp
// (no max subtraction: max_j s_ij >= diagonal-ish >> -87, safe in fp32).
// MSS importance weights folded in linearly: S = sum_j W_ij * exp(g_ij).
__global__ __launch_bounds__(256) void k_pair(const float* __restrict__ mu,
                                              const float* __restrict__ lv,
                                              const float* __restrict__ z,
                                              const int* __restrict__ nds,
                                              float* __restrict__ acc, int B) {
    const int i = blockIdx.x;

    // z row (uniform address -> scalar loads/broadcast)
    float v[16];
    const float* zi = z + i * 16;
    #pragma unroll
    for (int d = 0; d < 16; d++) v[d] = zi[d];

    const float Nf = (float)(*nds);
    const float Mf = (float)(B - 1);
    const float strat = (Nf - Mf) / (Nf * Mf);
    const float w0 = (i == B - 2) ? strat : (1.0f / Nf);
    const float w1 = strat;
    const float wm = 1.0f / Mf;

    float sd[16];
    #pragma unroll
    for (int d = 0; d < 16; d++) sd[d] = 0.0f;
    float stot = 0.0f;

    for (int j = threadIdx.x; j < B; j += 256) {
        const float4* m4 = (const float4*)(mu + j * 16);
        const float4* l4 = (const float4*)(lv + j * 16);
        float4 m0 = m4[0], m1 = m4[1], m2 = m4[2], m3 = m4[3];
        float4 l0 = l4[0], l1 = l4[1], l2 = l4[2], l3 = l4[3];
        float mj[16] = {m0.x, m0.y, m0.z, m0.w, m1.x, m1.y, m1.z, m1.w,
                        m2.x, m2.y, m2.z, m2.w, m3.x, m3.y, m3.z, m3.w};
        float lj[16] = {l0.x, l0.y, l0.z, l0.w, l1.x, l1.y, l1.z, l1.w,
                        l2.x, l2.y, l2.z, l2.w, l3.x, l3.y, l3.z, l3.w};
        float w = (j == 0) ? w0 : ((j == 1) ? w1 : wm);
        float s = 0.0f;
        #pragma unroll
        for (int d = 0; d < 16; d++) {
            float t = v[d] - mj[d];
            float is = __expf(-lj[d]);
            float g = -0.5f * (fmaf(t * t, is, lj[d]) + LOG2PI_F);
            s += g;
            sd[d] = fmaf(w, __expf(g), sd[d]);
        }
        stot = fmaf(w, __expf(s), stot);
    }

    // reduce 17 sums across the block (plain adds, linear domain)
    #pragma unroll
    for (int off = 32; off > 0; off >>= 1) {
        stot += __shfl_down(stot, off);
        #pragma unroll
        for (int d = 0; d < 16; d++) sd[d] += __shfl_down(sd[d], off);
    }
    __shared__ float red[4][17];
    int lane = threadIdx.x & 63, wave = threadIdx.x >> 6;
    if (lane == 0) {
        red[wave][0] = stot;
        #pragma unroll
        for (int d = 0; d < 16; d++) red[wave][1 + d] = sd[d];
    }
    __syncthreads();
    if (threadIdx.x == 0) {
        float S = red[0][0] + red[1][0] + red[2][0] + red[3][0];
        float lqzp = 0.0f;
        #pragma unroll
        for (int d = 0; d < 16; d++) {
            float Sd = red[0][1 + d] + red[1][1 + d] + red[2][1 + d] + red[3][1 + d];
            lqzp += logf(Sd);
        }
        atomicAdd(&acc[3], logf(S));
        atomicAdd(&acc[4], lqzp);
    }
}

__global__ void k_final(const float* __restrict__ acc, float* __restrict__ out,
                        float invBF, float invB) {
    // total = recon + E[lqzx] + 3 E[lqz] - 3 E[lqzp] - E[lprior]
    out[0] = acc[0] * invBF +
             (acc[1] + 3.0f * acc[3] - 3.0f * acc[4] - acc[2]) * invB;
}

extern "C" void kernel_launch(void* const* d_in, const int* in_sizes, int n_in,
                              void* d_out, int out_size, void* d_ws, size_t ws_size,
                              hipStream_t stream) {
    const float* x   = (const float*)d_in[0];
    const float* rec = (const float*)d_in[1];
    const float* mu  = (const float*)d_in[2];
    const float* lv  = (const float*)d_in[3];
    const float* z   = (const float*)d_in[4];
    const int*   nds = (const int*)d_in[5];

    const int BD = in_sizes[2];        // B * 16
    const int B  = BD / 16;
    const int BF = in_sizes[0];        // B * F
    const int n4 = BF / 4;

    float* acc = (float*)d_ws;

    k_zero<<<1, 64, 0, stream>>>(acc);
    k_recon<<<(n4 + 255) / 256, 256, 0, stream>>>((const float4*)x, (const float4*)rec, acc, n4);
    k_row<<<(BD + 255) / 256, 256, 0, stream>>>(mu, lv, z, acc, BD);
    k_pair<<<B, 256, 0, stream>>>(mu, lv, z, nds, acc, B);
    k_final<<<1, 1, 0, stream>>>(acc, (float*)d_out, 1.0f / (float)BF, 1.0f / (float)B);
}

// Round 2
// 127.941 us; speedup vs baseline: 1.1888x; 1.1888x over previous
//
#include <hip/hip_runtime.h>
#include <math.h>

#define LOG2PI_F 1.8378770664093453f
#define LOG2E_F  1.4426950408889634f
#define LN2_F    0.6931471805599453f
#define EXP_NEG1 0.36787944117144233f

__device__ __forceinline__ float exp2_(float x) { return __builtin_amdgcn_exp2f(x); }
__device__ __forceinline__ float log2_(float x) { return __builtin_amdgcn_logf(x); }

// acc layout (floats): [0]=recon [1]=lqzx [2]=lprior [3]=lqz [4]=lqzp
// AC layout: per row j, 64 floats: [0..15]=a  [16..31]=b  [32..47]=w*C'  [48]=w*prod(C')

__global__ __launch_bounds__(64) void k_zero(float* acc) {
    if (threadIdx.x < 8) acc[threadIdx.x] = 0.0f;
}

__global__ __launch_bounds__(256) void k_recon(const float4* __restrict__ x,
                                               const float4* __restrict__ r,
                                               float* __restrict__ acc, int n4) {
    float s = 0.0f;
    for (int idx = blockIdx.x * 256 + threadIdx.x; idx < n4; idx += gridDim.x * 256) {
        float4 a = x[idx], b = r[idx];
        s += fabsf(a.x - b.x) + fabsf(a.y - b.y) + fabsf(a.z - b.z) + fabsf(a.w - b.w);
    }
    #pragma unroll
    for (int off = 32; off > 0; off >>= 1) s += __shfl_down(s, off);
    __shared__ float red[4];
    int lane = threadIdx.x & 63, wv = threadIdx.x >> 6;
    if (lane == 0) red[wv] = s;
    __syncthreads();
    if (threadIdx.x == 0) atomicAdd(&acc[0], red[0] + red[1] + red[2] + red[3]);
}

// One thread per (j,d). Emits quadratic-form coefficients (log2 domain) with the
// MSS importance weight w_j folded in, plus the row product for the total-density
// logsumexp. Also accumulates lqzx and lprior sums (folding old k_row in).
__global__ __launch_bounds__(256) void k_prep(const float* __restrict__ mu,
                                              const float* __restrict__ lv,
                                              const float* __restrict__ z,
                                              const int* __restrict__ nds,
                                              float* __restrict__ AC,
                                              float* __restrict__ acc, int B) {
    int idx = blockIdx.x * 256 + threadIdx.x;     // 0 .. B*16-1
    int j = idx >> 4, d = idx & 15;
    float m = mu[idx], l = lv[idx], zz = z[idx];
    float is = __expf(-l);
    float a = -0.5f * LOG2E_F * is;               // exponent(v) = a*v^2 + b*v  (log2)
    float b = -2.0f * a * m;
    float ec = fmaf(-0.5f * LOG2E_F, l + LOG2PI_F, a * m * m);  // log2(C')

    float Nf = (float)(*nds);
    float Mf = (float)(B - 1);
    float strat = (Nf - Mf) / (Nf * Mf);
    float w = (j == 0) ? (1.0f / Nf) : ((j == 1) ? strat : (1.0f / Mf));

    float* row = AC + (size_t)j * 64;
    row[d] = a;
    row[16 + d] = b;
    row[32 + d] = w * exp2_(ec);

    // product over the 16 dims of this row = exp2(sum of ec) via intra-group shuffles
    float es = ec;
    es += __shfl_xor(es, 1); es += __shfl_xor(es, 2);
    es += __shfl_xor(es, 4); es += __shfl_xor(es, 8);
    if (d == 0) row[48] = w * exp2_(es);

    // lqzx / lprior elementwise contributions
    float t = zz - m;
    float ga = -0.5f * (fmaf(t * t, is, l) + LOG2PI_F);
    float gb = -0.5f * (fmaf(zz * zz, EXP_NEG1, 1.0f) + LOG2PI_F);
    #pragma unroll
    for (int off = 32; off > 0; off >>= 1) { ga += __shfl_down(ga, off); gb += __shfl_down(gb, off); }
    __shared__ float ra[4], rb[4];
    int lane = threadIdx.x & 63, wv = threadIdx.x >> 6;
    if (lane == 0) { ra[wv] = ga; rb[wv] = gb; }
    __syncthreads();
    if (threadIdx.x == 0) {
        atomicAdd(&acc[1], ra[0] + ra[1] + ra[2] + ra[3]);
        atomicAdd(&acc[2], rb[0] + rb[1] + rb[2] + rb[3]);
    }
}

// TI=4 rows of i per block, 256 threads: il = t&3, jg = t>>2 (64 j-lanes, 32 iters).
// Double-buffered register prefetch of the 13 float4 per j-row.
__global__ __launch_bounds__(256) void k_pair(const float4* __restrict__ AC4,
                                              const float* __restrict__ z,
                                              const int* __restrict__ nds,
                                              float* __restrict__ acc, int B) {
    const int il = threadIdx.x & 3;
    const int jg = threadIdx.x >> 2;
    const int i  = blockIdx.x * 4 + il;

    float v[16];
    const float* zi = z + (size_t)i * 16;
    #pragma unroll
    for (int d = 0; d < 16; d++) v[d] = zi[d];

    float sd[16];
    #pragma unroll
    for (int d = 0; d < 16; d++) sd[d] = 0.0f;
    float stot = 0.0f;

    const int nIt = B >> 6;
    float4 cur[13];
    {
        size_t r = (size_t)jg * 16;
        #pragma unroll
        for (int q = 0; q < 13; q++) cur[q] = AC4[r + q];
    }

    for (int it = 0; it < nIt; ++it) {
        int jn = jg + (it + 1) * 64;
        size_t rn = (size_t)(jn < B ? jn : jg) * 16;
        float4 nxt[13];
        #pragma unroll
        for (int q = 0; q < 13; q++) nxt[q] = AC4[rn + q];

        float s2a = 0.0f, s2b = 0.0f, e;
        #pragma unroll
        for (int q = 0; q < 4; q++) {
            float4 av = cur[q], bv = cur[q + 4], cv = cur[q + 8];
            const int d0 = q * 4;
            e = v[d0+0] * fmaf(av.x, v[d0+0], bv.x); s2a += e; sd[d0+0] = fmaf(cv.x, exp2_(e), sd[d0+0]);
            e = v[d0+1] * fmaf(av.y, v[d0+1], bv.y); s2b += e; sd[d0+1] = fmaf(cv.y, exp2_(e), sd[d0+1]);
            e = v[d0+2] * fmaf(av.z, v[d0+2], bv.z); s2a += e; sd[d0+2] = fmaf(cv.z, exp2_(e), sd[d0+2]);
            e = v[d0+3] * fmaf(av.w, v[d0+3], bv.w); s2b += e; sd[d0+3] = fmaf(cv.w, exp2_(e), sd[d0+3]);
        }
        stot = fmaf(cur[12].x, exp2_(s2a + s2b), stot);

        #pragma unroll
        for (int q = 0; q < 13; q++) cur[q] = nxt[q];
    }

    // reduce across the 16 threads sharing each i (lanes differing in bits >= 2)
    #pragma unroll
    for (int msk = 4; msk < 64; msk <<= 1) {
        stot += __shfl_xor(stot, msk);
        #pragma unroll
        for (int d = 0; d < 16; d++) sd[d] += __shfl_xor(sd[d], msk);
    }
    __shared__ float red[4][4][17];
    int lane = threadIdx.x & 63, wv = threadIdx.x >> 6;
    if (lane < 4) {
        red[wv][lane][0] = stot;
        #pragma unroll
        for (int d = 0; d < 16; d++) red[wv][lane][1 + d] = sd[d];
    }
    __syncthreads();
    if (threadIdx.x < 4) {   // il == threadIdx.x, v[] matches this i
        float S = red[0][il][0] + red[1][il][0] + red[2][il][0] + red[3][il][0];
        float Sd[16];
        #pragma unroll
        for (int d = 0; d < 16; d++)
            Sd[d] = red[0][il][1+d] + red[1][il][1+d] + red[2][il][1+d] + red[3][il][1+d];

        if (i == B - 2) {
            // W[B-2,0] = strat, but prep folded w0 = 1/N: patch with delta on row 0.
            const float* row0 = (const float*)AC4;
            float Nf = (float)(*nds);
            float Mf = (float)(B - 1);
            float strat = (Nf - Mf) / (Nf * Mf);
            float dw = strat - 1.0f / Nf;
            float s2 = 0.0f;
            #pragma unroll
            for (int d = 0; d < 16; d++) {
                float e = v[d] * fmaf(row0[d], v[d], row0[16 + d]);
                s2 += e;
                Sd[d] += dw * (row0[32 + d] * Nf) * exp2_(e);
            }
            S += dw * (row0[48] * Nf) * exp2_(s2);
        }

        float lqz  = log2_(S) * LN2_F;
        float lqzp = 0.0f;
        #pragma unroll
        for (int d = 0; d < 16; d++) lqzp += log2_(Sd[d]);
        lqzp *= LN2_F;
        lqz  += __shfl_xor(lqz, 1);  lqz  += __shfl_xor(lqz, 2);
        lqzp += __shfl_xor(lqzp, 1); lqzp += __shfl_xor(lqzp, 2);
        if (threadIdx.x == 0) { atomicAdd(&acc[3], lqz); atomicAdd(&acc[4], lqzp); }
    }
}

__global__ void k_final(const float* __restrict__ acc, float* __restrict__ out,
                        float invBF, float invB) {
    // total = recon + E[lqzx] + 3 E[lqz] - 3 E[lqzp] - E[lprior]
    out[0] = acc[0] * invBF +
             (acc[1] + 3.0f * acc[3] - 3.0f * acc[4] - acc[2]) * invB;
}

extern "C" void kernel_launch(void* const* d_in, const int* in_sizes, int n_in,
                              void* d_out, int out_size, void* d_ws, size_t ws_size,
                              hipStream_t stream) {
    const float* x   = (const float*)d_in[0];
    const float* rec = (const float*)d_in[1];
    const float* mu  = (const float*)d_in[2];
    const float* lv  = (const float*)d_in[3];
    const float* z   = (const float*)d_in[4];
    const int*   nds = (const int*)d_in[5];

    const int BD = in_sizes[2];        // B * 16
    const int B  = BD / 16;
    const int BF = in_sizes[0];        // B * F
    const int n4 = BF / 4;

    float* acc = (float*)d_ws;                       // 8 floats
    float* AC  = (float*)d_ws + 64;                  // B * 64 floats (aligned 256B)

    k_zero <<<1, 64, 0, stream>>>(acc);
    k_prep <<<(BD + 255) / 256, 256, 0, stream>>>(mu, lv, z, nds, AC, acc, B);
    k_recon<<<512, 256, 0, stream>>>((const float4*)x, (const float4*)rec, acc, n4);
    k_pair <<<B / 4, 256, 0, stream>>>((const float4*)AC, z, nds, acc, B);
    k_final<<<1, 1, 0, stream>>>(acc, (float*)d_out, 1.0f / (float)BF, 1.0f / (float)B);
}

// Round 4
// 101.322 us; speedup vs baseline: 1.5011x; 1.2627x over previous
//
#include <hip/hip_runtime.h>
#include <math.h>

#define LOG2PI_F 1.8378770664093453f
#define LOG2E_F  1.4426950408889634f
#define LN2_F    0.6931471805599453f
#define EXP_NEG1 0.36787944117144233f

#define TI   16      // i-rows per block
#define JSP  8       // j-splits (grid.y)
#define STG  64      // j-rows staged per LDS buffer
#define ROWF 52      // floats per AC row: a[16] b[16] c[16] prod [pad 3]

__device__ __forceinline__ float exp2_(float x) { return __builtin_amdgcn_exp2f(x); }
__device__ __forceinline__ float log2_(float x) { return __builtin_amdgcn_logf(x); }

// ws layout (floats): acc[0..7]: [0]=recon [1]=lqzx [2]=lprior [3]=lqz [4]=lqzp
//                     Racc[B*17]: per-i {stot, sd[16]} linear sums
//                     AC[B*52]: packed per-j coefficients

__global__ __launch_bounds__(256) void k_recon(const float4* __restrict__ x,
                                               const float4* __restrict__ r,
                                               float* __restrict__ acc, int n4) {
    float s = 0.0f;
    for (int idx = blockIdx.x * 256 + threadIdx.x; idx < n4; idx += gridDim.x * 256) {
        float4 a = x[idx], b = r[idx];
        s += fabsf(a.x - b.x) + fabsf(a.y - b.y) + fabsf(a.z - b.z) + fabsf(a.w - b.w);
    }
    #pragma unroll
    for (int off = 32; off > 0; off >>= 1) s += __shfl_down(s, off);
    __shared__ float red[4];
    int lane = threadIdx.x & 63, wv = threadIdx.x >> 6;
    if (lane == 0) red[wv] = s;
    __syncthreads();
    if (threadIdx.x == 0) atomicAdd(&acc[0], red[0] + red[1] + red[2] + red[3]);
}

// One thread per (j,d): quadratic-form coefficients in log2 domain, MSS weight folded.
__global__ __launch_bounds__(256) void k_prep(const float* __restrict__ mu,
                                              const float* __restrict__ lv,
                                              const float* __restrict__ z,
                                              const int* __restrict__ nds,
                                              float* __restrict__ AC,
                                              float* __restrict__ acc, int B) {
    int idx = blockIdx.x * 256 + threadIdx.x;
    int j = idx >> 4, d = idx & 15;
    float m = mu[idx], l = lv[idx], zz = z[idx];
    float is = __expf(-l);
    float a = -0.5f * LOG2E_F * is;                               // log2-domain
    float b = -2.0f * a * m;
    float ec = fmaf(-0.5f * LOG2E_F, l + LOG2PI_F, a * m * m);    // log2(C')

    float Nf = (float)(*nds);
    float Mf = (float)(B - 1);
    float strat = (Nf - Mf) / (Nf * Mf);
    float w = (j == 0) ? (1.0f / Nf) : ((j == 1) ? strat : (1.0f / Mf));

    float* row = AC + (size_t)j * ROWF;
    row[d] = a;
    row[16 + d] = b;
    row[32 + d] = w * exp2_(ec);
    float es = ec;
    es += __shfl_xor(es, 1); es += __shfl_xor(es, 2);
    es += __shfl_xor(es, 4); es += __shfl_xor(es, 8);
    if (d == 0) row[48] = w * exp2_(es);

    float t = zz - m;
    float ga = -0.5f * (fmaf(t * t, is, l) + LOG2PI_F);
    float gb = -0.5f * (fmaf(zz * zz, EXP_NEG1, 1.0f) + LOG2PI_F);
    #pragma unroll
    for (int off = 32; off > 0; off >>= 1) { ga += __shfl_down(ga, off); gb += __shfl_down(gb, off); }
    __shared__ float ra[4], rb[4];
    int lane = threadIdx.x & 63, wv = threadIdx.x >> 6;
    if (lane == 0) { ra[wv] = ga; rb[wv] = gb; }
    __syncthreads();
    if (threadIdx.x == 0) {
        atomicAdd(&acc[1], ra[0] + ra[1] + ra[2] + ra[3]);
        atomicAdd(&acc[2], rb[0] + rb[1] + rb[2] + rb[3]);
    }
}

#define DIM(AQ, BQ, CQ, comp, dd, SACC) \
    e = fmaf(AQ.comp, v2[dd], BQ.comp * v[dd]); SACC += e; \
    sd[dd] = fmaf(CQ.comp, exp2_(e), sd[dd]);

// grid (B/TI, JSP); block 256 = 16 il x 16 jg. LDS-staged j-tiles, broadcast reads.
__global__ __launch_bounds__(256) void k_pair(const float* __restrict__ AC,
                                              const float* __restrict__ z,
                                              float* __restrict__ Racc,
                                              int B, int jch) {
    __shared__ float sbuf[2][STG * ROWF];
    __shared__ float red[4][TI][17];

    const int il = threadIdx.x & 15;
    const int jg = threadIdx.x >> 4;
    const int i  = blockIdx.x * TI + il;
    const int jbase = blockIdx.y * jch;

    float v[16], v2[16];
    {
        const float4* zp = (const float4*)(z + (size_t)i * 16);
        float4 z0 = zp[0], z1 = zp[1], z2 = zp[2], z3 = zp[3];
        v[0]=z0.x; v[1]=z0.y; v[2]=z0.z; v[3]=z0.w;
        v[4]=z1.x; v[5]=z1.y; v[6]=z1.z; v[7]=z1.w;
        v[8]=z2.x; v[9]=z2.y; v[10]=z2.z; v[11]=z2.w;
        v[12]=z3.x; v[13]=z3.y; v[14]=z3.z; v[15]=z3.w;
        #pragma unroll
        for (int d = 0; d < 16; d++) v2[d] = v[d] * v[d];
    }

    float sd[16];
    #pragma unroll
    for (int d = 0; d < 16; d++) sd[d] = 0.0f;
    float stot = 0.0f;

    auto load_stage = [&](int buf, int st) {
        const float4* g = (const float4*)(AC + (size_t)(jbase + st * STG) * ROWF);
        float4* dst = (float4*)sbuf[buf];
        #pragma unroll
        for (int k = 0; k < 4; ++k) {
            int idx = threadIdx.x + k * 256;
            if (idx < (STG * ROWF) / 4) dst[idx] = g[idx];
        }
    };

    const int nst = jch / STG;
    load_stage(0, 0);
    __syncthreads();
    for (int st = 0; st < nst; ++st) {
        if (st + 1 < nst) load_stage((st + 1) & 1, st + 1);
        const float* base = sbuf[st & 1];
        #pragma unroll
        for (int k = 0; k < 4; ++k) {
            const float* rp = base + (jg + 16 * k) * ROWF;
            const float4* r4 = (const float4*)rp;
            float4 A0 = r4[0], A1 = r4[1], A2 = r4[2], A3 = r4[3];
            float4 Bv0 = r4[4], Bv1 = r4[5], Bv2 = r4[6], Bv3 = r4[7];
            float4 Cv0 = r4[8], Cv1 = r4[9], Cv2 = r4[10], Cv3 = r4[11];
            float  P = rp[48];
            float s2a = 0.0f, s2b = 0.0f, e;
            DIM(A0, Bv0, Cv0, x, 0, s2a)  DIM(A0, Bv0, Cv0, y, 1, s2b)
            DIM(A0, Bv0, Cv0, z, 2, s2a)  DIM(A0, Bv0, Cv0, w, 3, s2b)
            DIM(A1, Bv1, Cv1, x, 4, s2a)  DIM(A1, Bv1, Cv1, y, 5, s2b)
            DIM(A1, Bv1, Cv1, z, 6, s2a)  DIM(A1, Bv1, Cv1, w, 7, s2b)
            DIM(A2, Bv2, Cv2, x, 8, s2a)  DIM(A2, Bv2, Cv2, y, 9, s2b)
            DIM(A2, Bv2, Cv2, z, 10, s2a) DIM(A2, Bv2, Cv2, w, 11, s2b)
            DIM(A3, Bv3, Cv3, x, 12, s2a) DIM(A3, Bv3, Cv3, y, 13, s2b)
            DIM(A3, Bv3, Cv3, z, 14, s2a) DIM(A3, Bv3, Cv3, w, 15, s2b)
            stot = fmaf(P, exp2_(s2a + s2b), stot);
        }
        __syncthreads();
    }

    // reduce over jg within wave (jg bits 0-1 = lane bits 4-5)
    #pragma unroll
    for (int msk = 16; msk <= 32; msk <<= 1) {
        stot += __shfl_xor(stot, msk);
        #pragma unroll
        for (int d = 0; d < 16; d++) sd[d] += __shfl_xor(sd[d], msk);
    }
    int lane = threadIdx.x & 63, wv = threadIdx.x >> 6;
    if (lane < 16) {
        red[wv][lane][0] = stot;
        #pragma unroll
        for (int d = 0; d < 16; d++) red[wv][lane][1 + d] = sd[d];
    }
    __syncthreads();
    // TI*17 = 272 > 256: MUST loop (round-3 bug: trailing 16 entries never summed)
    for (int t = threadIdx.x; t < TI * 17; t += 256) {
        int il2 = t / 17, c = t % 17;
        float s = red[0][il2][c] + red[1][il2][c] + red[2][il2][c] + red[3][il2][c];
        atomicAdd(&Racc[(size_t)(blockIdx.x * TI + il2) * 17 + c], s);
    }
}

// One thread per i: logs + W[B-2,0] patch, reduce to acc[3], acc[4].
__global__ __launch_bounds__(256) void k_logs(const float* __restrict__ Racc,
                                              const float* __restrict__ AC,
                                              const float* __restrict__ z,
                                              const int* __restrict__ nds,
                                              float* __restrict__ acc, int B) {
    int i = blockIdx.x * 256 + threadIdx.x;
    const float* R = Racc + (size_t)i * 17;
    float S = R[0];
    float Sd[16];
    #pragma unroll
    for (int d = 0; d < 16; d++) Sd[d] = R[1 + d];

    if (i == B - 2) {
        // prep folded w0 = 1/N into row 0, but W[B-2,0] = strat: add delta.
        const float* row0 = AC;
        const float* vv = z + (size_t)i * 16;
        float Nf = (float)(*nds);
        float Mf = (float)(B - 1);
        float strat = (Nf - Mf) / (Nf * Mf);
        float dwN = (strat - 1.0f / Nf) * Nf;
        float s2 = 0.0f;
        #pragma unroll
        for (int d = 0; d < 16; d++) {
            float vd = vv[d];
            float e = fmaf(row0[d], vd * vd, row0[16 + d] * vd);
            s2 += e;
            Sd[d] += dwN * row0[32 + d] * exp2_(e);
        }
        S += dwN * row0[48] * exp2_(s2);
    }

    float lqz = log2_(S) * LN2_F;
    float lqzp = 0.0f;
    #pragma unroll
    for (int d = 0; d < 16; d++) lqzp += log2_(Sd[d]);
    lqzp *= LN2_F;

    #pragma unroll
    for (int off = 32; off > 0; off >>= 1) {
        lqz += __shfl_down(lqz, off);
        lqzp += __shfl_down(lqzp, off);
    }
    __shared__ float ra[4], rb[4];
    int lane = threadIdx.x & 63, wv = threadIdx.x >> 6;
    if (lane == 0) { ra[wv] = lqz; rb[wv] = lqzp; }
    __syncthreads();
    if (threadIdx.x == 0) {
        atomicAdd(&acc[3], ra[0] + ra[1] + ra[2] + ra[3]);
        atomicAdd(&acc[4], rb[0] + rb[1] + rb[2] + rb[3]);
    }
}

__global__ void k_final(const float* __restrict__ acc, float* __restrict__ out,
                        float invBF, float invB) {
    out[0] = acc[0] * invBF +
             (acc[1] + 3.0f * acc[3] - 3.0f * acc[4] - acc[2]) * invB;
}

extern "C" void kernel_launch(void* const* d_in, const int* in_sizes, int n_in,
                              void* d_out, int out_size, void* d_ws, size_t ws_size,
                              hipStream_t stream) {
    const float* x   = (const float*)d_in[0];
    const float* rec = (const float*)d_in[1];
    const float* mu  = (const float*)d_in[2];
    const float* lv  = (const float*)d_in[3];
    const float* z   = (const float*)d_in[4];
    const int*   nds = (const int*)d_in[5];

    const int BD = in_sizes[2];        // B * 16
    const int B  = BD / 16;
    const int BF = in_sizes[0];        // B * F
    const int n4 = BF / 4;

    float* acc  = (float*)d_ws;                    // 8 floats
    float* Racc = acc + 8;                         // B*17 floats
    float* AC   = Racc + (size_t)B * 17;           // B*52 floats (16B-aligned)

    hipMemsetAsync(d_ws, 0, (8 + (size_t)B * 17) * sizeof(float), stream);
    k_prep <<<BD / 256, 256, 0, stream>>>(mu, lv, z, nds, AC, acc, B);
    k_recon<<<512, 256, 0, stream>>>((const float4*)x, (const float4*)rec, acc, n4);
    dim3 gp(B / TI, JSP);
    k_pair <<<gp, 256, 0, stream>>>(AC, z, Racc, B, B / JSP);
    k_logs <<<B / 256, 256, 0, stream>>>(Racc, AC, z, nds, acc, B);
    k_final<<<1, 1, 0, stream>>>(acc, (float*)d_out, 1.0f / (float)BF, 1.0f / (float)B);
}